// Round 1
// baseline (23719.038 us; speedup 1.0000x reference)
//
#include <hip/hip_runtime.h>
#include <cstdint>
#include <cstddef>

// RNNLayer: B=64, T=1024, IN=512, H=512, fp32 in/out.
// Phase 1: Wx = X @ W_w^T + W_b  (f16 MFMA GEMM, fp32 accumulate) -> written into d_out.
// Phase 2: persistent scan, 256 WGs = 64 batches x 4 j-slices; U resident in VGPRs (f16x2),
//          h exchanged via d_out (Wx read then overwritten in place), per-batch flag sync.

#define T_STEPS 1024

using f16 = _Float16;
typedef f16  f16x2 __attribute__((ext_vector_type(2)));
typedef f16  f16x8 __attribute__((ext_vector_type(8)));
typedef float f32x4 __attribute__((ext_vector_type(4)));

#if __has_builtin(__builtin_amdgcn_fdot2)
#define FDOT2(a, b, c) __builtin_amdgcn_fdot2((a), (b), (c), false)
#else
static __device__ __forceinline__ float FDOT2(f16x2 a, f16x2 b, float c) {
    return c + (float)a[0] * (float)b[0] + (float)a[1] * (float)b[1];
}
#endif

// ---------------------------------------------------------------------------
// Kernel 1: Wx GEMM.  C[m,n] = sum_k X[m,k] * W[n,k] + Wb[n]
// 128x128 tile, BK=64, 256 threads (4 waves, each owns a 64x64 quadrant).
// f32 global -> convert to f16 in registers -> swizzled LDS -> mfma 16x16x32 f16.
// ---------------------------------------------------------------------------
__global__ __launch_bounds__(256, 2)
void gemm_wx(const float* __restrict__ X, const float* __restrict__ W,
             const float* __restrict__ Wb, float* __restrict__ out) {
    // 128 rows x 64 f16 = 128 bytes/row; XOR swizzle byte ^= (row&7)<<4 (G4 fix)
    __shared__ __align__(16) char Al[128 * 128];
    __shared__ __align__(16) char Bl[128 * 128];

    const int tid  = threadIdx.x;
    const int lane = tid & 63;
    const int wid  = tid >> 6;
    const int wm   = wid & 1;       // wave row quadrant (0..1)
    const int wn   = wid >> 1;      // wave col quadrant (0..1)
    const int m0   = blockIdx.x * 128;
    const int n0   = blockIdx.y * 128;

    f32x4 acc[4][4] = {};

    for (int kt = 0; kt < 512; kt += 64) {
        __syncthreads();   // protect LDS reuse from previous iteration's reads
        // Stage A (X rows) and B (W rows): 128x64 f16 each.
        // 1024 chunks of 8 floats; 256 threads x 4 chunks.
#pragma unroll
        for (int i = 0; i < 4; ++i) {
            const int id   = tid + i * 256;
            const int row  = id >> 3;        // 0..127
            const int slot = id & 7;         // 8-float chunk within row
            const float4* pa = reinterpret_cast<const float4*>(
                X + (size_t)(m0 + row) * 512 + kt + slot * 8);
            const float4* pb = reinterpret_cast<const float4*>(
                W + (size_t)(n0 + row) * 512 + kt + slot * 8);
            float4 a0 = pa[0], a1 = pa[1];
            float4 b0 = pb[0], b1 = pb[1];
            f16x8 va = { (f16)a0.x, (f16)a0.y, (f16)a0.z, (f16)a0.w,
                         (f16)a1.x, (f16)a1.y, (f16)a1.z, (f16)a1.w };
            f16x8 vb = { (f16)b0.x, (f16)b0.y, (f16)b0.z, (f16)b0.w,
                         (f16)b1.x, (f16)b1.y, (f16)b1.z, (f16)b1.w };
            const int cb = (slot * 16) ^ ((row & 7) << 4);
            *reinterpret_cast<f16x8*>(Al + row * 128 + cb) = va;
            *reinterpret_cast<f16x8*>(Bl + row * 128 + cb) = vb;
        }
        __syncthreads();

#pragma unroll
        for (int kk = 0; kk < 2; ++kk) {   // two k=32 sub-steps of BK=64
            f16x8 af[4], bf[4];
#pragma unroll
            for (int mi = 0; mi < 4; ++mi) {
                const int r  = wm * 64 + mi * 16 + (lane & 15);
                const int cb = (kk * 64 + ((lane >> 4) * 16)) ^ ((r & 7) << 4);
                af[mi] = *reinterpret_cast<const f16x8*>(Al + r * 128 + cb);
            }
#pragma unroll
            for (int ni = 0; ni < 4; ++ni) {
                const int r  = wn * 64 + ni * 16 + (lane & 15);
                const int cb = (kk * 64 + ((lane >> 4) * 16)) ^ ((r & 7) << 4);
                bf[ni] = *reinterpret_cast<const f16x8*>(Bl + r * 128 + cb);
            }
#pragma unroll
            for (int mi = 0; mi < 4; ++mi)
#pragma unroll
                for (int ni = 0; ni < 4; ++ni)
                    acc[mi][ni] = __builtin_amdgcn_mfma_f32_16x16x32_f16(
                        af[mi], bf[ni], acc[mi][ni], 0, 0, 0);
        }
    }

    // Epilogue: D layout col = lane&15, row = (lane>>4)*4 + e  (measured m89)
#pragma unroll
    for (int ni = 0; ni < 4; ++ni) {
        const int col  = n0 + wn * 64 + ni * 16 + (lane & 15);
        const float bias = Wb[col];
#pragma unroll
        for (int mi = 0; mi < 4; ++mi) {
            const int rowb = m0 + wm * 64 + mi * 16 + ((lane >> 4) * 4);
#pragma unroll
            for (int e = 0; e < 4; ++e)
                out[(size_t)(rowb + e) * 512 + col] = acc[mi][ni][e] + bias;
        }
    }
}

// ---------------------------------------------------------------------------
// Kernel 2: persistent scan.
// 256 WGs x 256 threads. WG (b, s) owns batch b, output rows [s*128, s*128+128).
// Thread (jl, kh): output row jl of the slice, k-half kh (256 of 512 k values).
// U slice held in 128 packed-f16 VGPRs per thread.  h_t lives in d_out:
// step t reads Wx at out[b,t,:own slice], reads h_{t-1}=out[b,t-1,:], writes h_t.
// 4 WGs of a batch sync via flags[b] (device-scope atomics -> XCD-placement safe).
// ---------------------------------------------------------------------------
__global__ __launch_bounds__(256, 1)
void rnn_scan(float* __restrict__ out, const float* __restrict__ h0,
              const float* __restrict__ Uw, const float* __restrict__ Ub,
              unsigned* __restrict__ flags) {
    const int tid = threadIdx.x;
    const int blk = blockIdx.x;
    // 4 WGs of a batch land on the same XCD under round-robin blockIdx%8 mapping
    const int b  = (blk & 7) * 8 + ((blk >> 3) & 7);
    const int s  = blk >> 6;            // j-slice 0..3
    const int jl = tid >> 1;            // 0..127 output row within slice
    const int kh = tid & 1;             // k half
    const int jg = s * 128 + jl;        // global output row (H index)

    // Load U[jg, kh*256 .. +255] as 128 packed f16x2 registers (loop-invariant).
    f16x2 u[128];
    {
        const float2* up = reinterpret_cast<const float2*>(
            Uw + (size_t)jg * 512 + kh * 256);
#pragma unroll
        for (int r = 0; r < 128; ++r) {
            float2 v = up[r];
            u[r] = (f16x2){ (f16)v.x, (f16)v.y };
        }
    }
    const float ub = Ub[jg];

    __shared__ __align__(16) unsigned hsh[256];   // 512 h values as f16x2

    float* const obase      = out + (size_t)b * (T_STEPS * 512);
    const float* const h0b  = h0 + b * 512;
    unsigned* const flg     = flags + b;

    for (int t = 0; t < T_STEPS; ++t) {
        // Wx for this step: written by gemm_wx, only ever touched by this WG.
        // Issue before the sync gate to hide latency.
        const float wx = obase[(size_t)t * 512 + jg];

        if (t > 0) {
            if (tid == 0) {
                while (__hip_atomic_load(flg, __ATOMIC_ACQUIRE,
                                         __HIP_MEMORY_SCOPE_AGENT) < (unsigned)(4 * t)) { }
            }
            __syncthreads();
        }

        // Stage h_{t-1} (full 512 floats) into LDS as f16x2.
        {
            const float* hsrc = (t == 0) ? h0b : (obase + (size_t)(t - 1) * 512);
            const float hx = __hip_atomic_load(hsrc + 2 * tid,     __ATOMIC_RELAXED,
                                               __HIP_MEMORY_SCOPE_AGENT);
            const float hy = __hip_atomic_load(hsrc + 2 * tid + 1, __ATOMIC_RELAXED,
                                               __HIP_MEMORY_SCOPE_AGENT);
            f16x2 p = { (f16)hx, (f16)hy };
            hsh[tid] = __builtin_bit_cast(unsigned, p);
        }
        __syncthreads();

        // 256-MAC dot: 128 v_dot2_f32_f16, 4 accumulators to break the dep chain.
        float a0 = 0.f, a1 = 0.f, a2 = 0.f, a3 = 0.f;
        const uint4* hp = reinterpret_cast<const uint4*>(
            reinterpret_cast<const char*>(hsh) + kh * 512);
#pragma unroll
        for (int r = 0; r < 32; ++r) {
            const uint4 hv = hp[r];   // ds_read_b128, broadcast across even/odd lanes
            a0 = FDOT2(u[4 * r + 0], __builtin_bit_cast(f16x2, hv.x), a0);
            a1 = FDOT2(u[4 * r + 1], __builtin_bit_cast(f16x2, hv.y), a1);
            a2 = FDOT2(u[4 * r + 2], __builtin_bit_cast(f16x2, hv.z), a2);
            a3 = FDOT2(u[4 * r + 3], __builtin_bit_cast(f16x2, hv.w), a3);
        }
        float acc = (a0 + a1) + (a2 + a3);
        acc += __shfl_xor(acc, 1);    // combine the two k-halves of the pair

        if (kh == 0) {
            const float a  = wx + acc + ub;
            const float ax = fabsf(a);
            const float e  = __expf(2.0f * ax);
            const float r1 = 1.0f - 2.0f / (e + 1.0f);   // tanh(|a|); e=inf -> 1
            __hip_atomic_store(&obase[(size_t)t * 512 + jg], copysignf(r1, a),
                               __ATOMIC_RELAXED, __HIP_MEMORY_SCOPE_AGENT);
        }
        __threadfence();      // make h_t stores agent-visible before the flag bump
        __syncthreads();
        if (tid == 0)
            __hip_atomic_fetch_add(flg, 1u, __ATOMIC_RELEASE,
                                   __HIP_MEMORY_SCOPE_AGENT);
    }
}

// ---------------------------------------------------------------------------
extern "C" void kernel_launch(void* const* d_in, const int* in_sizes, int n_in,
                              void* d_out, int out_size, void* d_ws, size_t ws_size,
                              hipStream_t stream) {
    const float* X  = (const float*)d_in[0];
    const float* h0 = (const float*)d_in[1];
    const float* Ww = (const float*)d_in[2];
    const float* Wb = (const float*)d_in[3];
    const float* Uw = (const float*)d_in[4];
    const float* Ub = (const float*)d_in[5];
    float* out = (float*)d_out;
    unsigned* flags = (unsigned*)d_ws;

    // zero the 64 per-batch flag counters (graph-replay safe: captured in graph)
    hipMemsetAsync(d_ws, 0, 256, stream);

    // Phase 1: Wx + bias into d_out.  M=65536 -> 512 tiles, N=512 -> 4 tiles.
    gemm_wx<<<dim3(512, 4), dim3(256), 0, stream>>>(X, Ww, Wb, out);

    // Phase 2: persistent scan. 256 WGs, 1/CU worst case -> all co-resident.
    rnn_scan<<<dim3(256), dim3(256), 0, stream>>>(out, h0, Uw, Ub, flags);
}

// Round 2
// 2860.068 us; speedup vs baseline: 8.2932x; 8.2932x over previous
//
#include <hip/hip_runtime.h>
#include <cstdint>
#include <cstddef>

// RNNLayer: B=64, T=1024, IN=512, H=512, fp32 in/out.
// Phase 1: Wx = X @ W_w^T + W_b  (f16 MFMA GEMM, fp32 accumulate) -> written into d_out.
// Phase 2: scan with ONE workgroup per batch (1024 threads, 16 waves, 1 CU).
//          No cross-WG sync. U resident in VGPRs (f16x2). h double-buffered in LDS.

#define T_STEPS 1024

using f16 = _Float16;
typedef f16  f16x2 __attribute__((ext_vector_type(2)));
typedef f16  f16x8 __attribute__((ext_vector_type(8)));
typedef float f32x4 __attribute__((ext_vector_type(4)));

#if __has_builtin(__builtin_amdgcn_fdot2)
#define FDOT2(a, b, c) __builtin_amdgcn_fdot2((a), (b), (c), false)
#else
static __device__ __forceinline__ float FDOT2(f16x2 a, f16x2 b, float c) {
    return c + (float)a[0] * (float)b[0] + (float)a[1] * (float)b[1];
}
#endif

// ---------------------------------------------------------------------------
// Kernel 1: Wx GEMM.  C[m,n] = sum_k X[m,k] * W[n,k] + Wb[n]
// 128x128 tile, BK=64, 256 threads (4 waves, each owns a 64x64 quadrant).
// f32 global -> convert to f16 in registers -> swizzled LDS -> mfma 16x16x32 f16.
// ---------------------------------------------------------------------------
__global__ __launch_bounds__(256, 2)
void gemm_wx(const float* __restrict__ X, const float* __restrict__ W,
             const float* __restrict__ Wb, float* __restrict__ out) {
    __shared__ __align__(16) char Al[128 * 128];
    __shared__ __align__(16) char Bl[128 * 128];

    const int tid  = threadIdx.x;
    const int lane = tid & 63;
    const int wid  = tid >> 6;
    const int wm   = wid & 1;
    const int wn   = wid >> 1;
    const int m0   = blockIdx.x * 128;
    const int n0   = blockIdx.y * 128;

    f32x4 acc[4][4] = {};

    for (int kt = 0; kt < 512; kt += 64) {
        __syncthreads();
#pragma unroll
        for (int i = 0; i < 4; ++i) {
            const int id   = tid + i * 256;
            const int row  = id >> 3;
            const int slot = id & 7;
            const float4* pa = reinterpret_cast<const float4*>(
                X + (size_t)(m0 + row) * 512 + kt + slot * 8);
            const float4* pb = reinterpret_cast<const float4*>(
                W + (size_t)(n0 + row) * 512 + kt + slot * 8);
            float4 a0 = pa[0], a1 = pa[1];
            float4 b0 = pb[0], b1 = pb[1];
            f16x8 va = { (f16)a0.x, (f16)a0.y, (f16)a0.z, (f16)a0.w,
                         (f16)a1.x, (f16)a1.y, (f16)a1.z, (f16)a1.w };
            f16x8 vb = { (f16)b0.x, (f16)b0.y, (f16)b0.z, (f16)b0.w,
                         (f16)b1.x, (f16)b1.y, (f16)b1.z, (f16)b1.w };
            const int cb = (slot * 16) ^ ((row & 7) << 4);
            *reinterpret_cast<f16x8*>(Al + row * 128 + cb) = va;
            *reinterpret_cast<f16x8*>(Bl + row * 128 + cb) = vb;
        }
        __syncthreads();

#pragma unroll
        for (int kk = 0; kk < 2; ++kk) {
            f16x8 af[4], bf[4];
#pragma unroll
            for (int mi = 0; mi < 4; ++mi) {
                const int r  = wm * 64 + mi * 16 + (lane & 15);
                const int cb = (kk * 64 + ((lane >> 4) * 16)) ^ ((r & 7) << 4);
                af[mi] = *reinterpret_cast<const f16x8*>(Al + r * 128 + cb);
            }
#pragma unroll
            for (int ni = 0; ni < 4; ++ni) {
                const int r  = wn * 64 + ni * 16 + (lane & 15);
                const int cb = (kk * 64 + ((lane >> 4) * 16)) ^ ((r & 7) << 4);
                bf[ni] = *reinterpret_cast<const f16x8*>(Bl + r * 128 + cb);
            }
#pragma unroll
            for (int mi = 0; mi < 4; ++mi)
#pragma unroll
                for (int ni = 0; ni < 4; ++ni)
                    acc[mi][ni] = __builtin_amdgcn_mfma_f32_16x16x32_f16(
                        af[mi], bf[ni], acc[mi][ni], 0, 0, 0);
        }
    }

#pragma unroll
    for (int ni = 0; ni < 4; ++ni) {
        const int col  = n0 + wn * 64 + ni * 16 + (lane & 15);
        const float bias = Wb[col];
#pragma unroll
        for (int mi = 0; mi < 4; ++mi) {
            const int rowb = m0 + wm * 64 + mi * 16 + ((lane >> 4) * 4);
#pragma unroll
            for (int e = 0; e < 4; ++e)
                out[(size_t)(rowb + e) * 512 + col] = acc[mi][ni][e] + bias;
        }
    }
}

// ---------------------------------------------------------------------------
// Kernel 2: scan. One WG (1024 threads) per batch; h double-buffered in LDS.
// Thread (j = tid>>1, kh = tid&1): output row j, k-half kh.
// U[j, kh*256..+255] in 128 f16x2 VGPRs. One __syncthreads per step.
// h halves padded 528B apart -> the two per-wave broadcast lines hit
// disjoint banks (0-3 vs 4-7): zero LDS bank conflicts.
// ---------------------------------------------------------------------------
__global__ __launch_bounds__(1024)
void rnn_scan(float* __restrict__ out, const float* __restrict__ h0,
              const float* __restrict__ Uw, const float* __restrict__ Ub) {
    const int tid = threadIdx.x;
    const int b   = blockIdx.x;
    const int j   = tid >> 1;        // output row 0..511
    const int kh  = tid & 1;         // k half

    // U slice -> 128 packed f16x2 registers (loop-invariant).
    f16x2 u[128];
    {
        const float2* up = reinterpret_cast<const float2*>(
            Uw + (size_t)j * 512 + kh * 256);
#pragma unroll
        for (int r = 0; r < 128; ++r) {
            float2 v = up[r];
            u[r] = (f16x2){ (f16)v.x, (f16)v.y };
        }
    }
    const float ub = Ub[j];

    // Two h buffers, each 512 f16 with a 16B pad between the k-halves.
    __shared__ __align__(16) char hbuf[2][1040];

    float* const obase = out + (size_t)b * (T_STEPS * 512);

    // Stage h_0 into hbuf[0].
    if (tid < 256) {
        const float2 v = reinterpret_cast<const float2*>(h0 + b * 512)[tid];
        f16x2 p = { (f16)v.x, (f16)v.y };
        *reinterpret_cast<unsigned*>(hbuf[0] + 4 * tid + (tid >= 128 ? 16 : 0)) =
            __builtin_bit_cast(unsigned, p);
    }
    float wx = (kh == 0) ? obase[j] : 0.0f;   // Wx row 0 (gemm_wx already done)
    __syncthreads();

    for (int t = 0; t < T_STEPS; ++t) {
        // Prefetch next step's Wx immediately (hides HBM latency under compute).
        float wxn = 0.0f;
        if (kh == 0 && t < T_STEPS - 1)
            wxn = obase[(size_t)(t + 1) * 512 + j];

        // 256-MAC dot from LDS broadcast reads; 4 accumulators break the chain.
        const uint4* hp = reinterpret_cast<const uint4*>(hbuf[t & 1] + kh * 528);
        float a0 = 0.f, a1 = 0.f, a2 = 0.f, a3 = 0.f;
#pragma unroll
        for (int r = 0; r < 32; ++r) {
            const uint4 hv = hp[r];
            a0 = FDOT2(u[4 * r + 0], __builtin_bit_cast(f16x2, hv.x), a0);
            a1 = FDOT2(u[4 * r + 1], __builtin_bit_cast(f16x2, hv.y), a1);
            a2 = FDOT2(u[4 * r + 2], __builtin_bit_cast(f16x2, hv.z), a2);
            a3 = FDOT2(u[4 * r + 3], __builtin_bit_cast(f16x2, hv.w), a3);
        }
        float acc = (a0 + a1) + (a2 + a3);
        acc += __shfl_xor(acc, 1);   // combine the two k-halves

        if (kh == 0) {
            const float a  = wx + acc + ub;
            const float ax = fabsf(a);
            const float e  = __expf(2.0f * ax);
            const float r1 = 1.0f - 2.0f / (e + 1.0f);     // tanh(|a|); e=inf -> 1
            const float h  = copysignf(r1, a);
            *reinterpret_cast<f16*>(hbuf[(t + 1) & 1] + 2 * j + (j >= 256 ? 16 : 0)) = (f16)h;
            obase[(size_t)t * 512 + j] = h;                // overwrite consumed Wx
        }
        wx = wxn;
        __syncthreads();   // h_t LDS writes visible; prev-buffer reads done
    }
}

// ---------------------------------------------------------------------------
extern "C" void kernel_launch(void* const* d_in, const int* in_sizes, int n_in,
                              void* d_out, int out_size, void* d_ws, size_t ws_size,
                              hipStream_t stream) {
    const float* X  = (const float*)d_in[0];
    const float* h0 = (const float*)d_in[1];
    const float* Ww = (const float*)d_in[2];
    const float* Wb = (const float*)d_in[3];
    const float* Uw = (const float*)d_in[4];
    const float* Ub = (const float*)d_in[5];
    float* out = (float*)d_out;

    // Phase 1: Wx + bias into d_out.  M=65536 -> 512 tiles, N=512 -> 4 tiles.
    gemm_wx<<<dim3(512, 4), dim3(256), 0, stream>>>(X, Ww, Wb, out);

    // Phase 2: scan. 64 WGs x 1024 threads, one per batch, no cross-WG sync.
    rnn_scan<<<dim3(64), dim3(1024), 0, stream>>>(out, h0, Uw, Ub);
}

// Round 3
// 2334.883 us; speedup vs baseline: 10.1586x; 1.2249x over previous
//
#include <hip/hip_runtime.h>
#include <cstdint>
#include <cstddef>

// RNNLayer: B=64, T=1024, IN=512, H=512, fp32 in/out.
// Phase 1: Wx = X @ W_w^T + W_b  (f16 MFMA GEMM) -> d_out.
// Phase 2: scan, one WG (512 threads, 8 waves) per batch, one CU per batch.
//   Thread j owns output row j. U[j,0:448) resident in 224 f16x2 VGPRs,
//   U[j,448:512) in swizzled LDS (64KB). h broadcast via readlane->SGPR feeding
//   v_dot2_f32_f16 (no per-thread LDS broadcast reads, no scratch).

#define T_STEPS 1024

using f16 = _Float16;
typedef f16  f16x2 __attribute__((ext_vector_type(2)));
typedef f16  f16x8 __attribute__((ext_vector_type(8)));
typedef float f32x4 __attribute__((ext_vector_type(4)));

#if __has_builtin(__builtin_amdgcn_fdot2)
#define FDOT2(a, b, c) __builtin_amdgcn_fdot2((a), (b), (c), false)
#else
static __device__ __forceinline__ float FDOT2(f16x2 a, f16x2 b, float c) {
    return c + (float)a[0] * (float)b[0] + (float)a[1] * (float)b[1];
}
#endif

static __device__ __forceinline__ f16x2 bcast_pair(int v) {
    return __builtin_bit_cast(f16x2, v);
}

// ---------------------------------------------------------------------------
// Kernel 1: Wx GEMM (unchanged from round 2; ~60-150us, not the bottleneck).
// ---------------------------------------------------------------------------
__global__ __launch_bounds__(256, 2)
void gemm_wx(const float* __restrict__ X, const float* __restrict__ W,
             const float* __restrict__ Wb, float* __restrict__ out) {
    __shared__ __align__(16) char Al[128 * 128];
    __shared__ __align__(16) char Bl[128 * 128];

    const int tid  = threadIdx.x;
    const int lane = tid & 63;
    const int wid  = tid >> 6;
    const int wm   = wid & 1;
    const int wn   = wid >> 1;
    const int m0   = blockIdx.x * 128;
    const int n0   = blockIdx.y * 128;

    f32x4 acc[4][4] = {};

    for (int kt = 0; kt < 512; kt += 64) {
        __syncthreads();
#pragma unroll
        for (int i = 0; i < 4; ++i) {
            const int id   = tid + i * 256;
            const int row  = id >> 3;
            const int slot = id & 7;
            const float4* pa = reinterpret_cast<const float4*>(
                X + (size_t)(m0 + row) * 512 + kt + slot * 8);
            const float4* pb = reinterpret_cast<const float4*>(
                W + (size_t)(n0 + row) * 512 + kt + slot * 8);
            float4 a0 = pa[0], a1 = pa[1];
            float4 b0 = pb[0], b1 = pb[1];
            f16x8 va = { (f16)a0.x, (f16)a0.y, (f16)a0.z, (f16)a0.w,
                         (f16)a1.x, (f16)a1.y, (f16)a1.z, (f16)a1.w };
            f16x8 vb = { (f16)b0.x, (f16)b0.y, (f16)b0.z, (f16)b0.w,
                         (f16)b1.x, (f16)b1.y, (f16)b1.z, (f16)b1.w };
            const int cb = (slot * 16) ^ ((row & 7) << 4);
            *reinterpret_cast<f16x8*>(Al + row * 128 + cb) = va;
            *reinterpret_cast<f16x8*>(Bl + row * 128 + cb) = vb;
        }
        __syncthreads();

#pragma unroll
        for (int kk = 0; kk < 2; ++kk) {
            f16x8 af[4], bf[4];
#pragma unroll
            for (int mi = 0; mi < 4; ++mi) {
                const int r  = wm * 64 + mi * 16 + (lane & 15);
                const int cb = (kk * 64 + ((lane >> 4) * 16)) ^ ((r & 7) << 4);
                af[mi] = *reinterpret_cast<const f16x8*>(Al + r * 128 + cb);
            }
#pragma unroll
            for (int ni = 0; ni < 4; ++ni) {
                const int r  = wn * 64 + ni * 16 + (lane & 15);
                const int cb = (kk * 64 + ((lane >> 4) * 16)) ^ ((r & 7) << 4);
                bf[ni] = *reinterpret_cast<const f16x8*>(Bl + r * 128 + cb);
            }
#pragma unroll
            for (int mi = 0; mi < 4; ++mi)
#pragma unroll
                for (int ni = 0; ni < 4; ++ni)
                    acc[mi][ni] = __builtin_amdgcn_mfma_f32_16x16x32_f16(
                        af[mi], bf[ni], acc[mi][ni], 0, 0, 0);
        }
    }

#pragma unroll
    for (int ni = 0; ni < 4; ++ni) {
        const int col  = n0 + wn * 64 + ni * 16 + (lane & 15);
        const float bias = Wb[col];
#pragma unroll
        for (int mi = 0; mi < 4; ++mi) {
            const int rowb = m0 + wm * 64 + mi * 16 + ((lane >> 4) * 4);
#pragma unroll
            for (int e = 0; e < 4; ++e)
                out[(size_t)(rowb + e) * 512 + col] = acc[mi][ni][e] + bias;
        }
    }
}

// ---------------------------------------------------------------------------
// Kernel 2: scan.
// ---------------------------------------------------------------------------
#define KREG   448                 // k-range held in VGPRs (224 f16x2)
#define NPREG  (KREG / 2)          // 224

__global__ __launch_bounds__(512, 2)
void rnn_scan(float* __restrict__ out, const float* __restrict__ h0,
              const float* __restrict__ Uw, const float* __restrict__ Ub) {
    const int tid  = threadIdx.x;      // = output row j (0..511)
    const int b    = blockIdx.x;
    const int lane = tid & 63;

    // U[j, 0:448) -> 224 packed f16x2 VGPRs (loop-invariant, truly resident:
    // 8 waves * 256-VGPR budget).
    f16x2 u[NPREG];
    {
        const float2* up = reinterpret_cast<const float2*>(Uw + (size_t)tid * 512);
#pragma unroll
        for (int p = 0; p < NPREG; ++p) {
            float2 v = up[p];
            u[p] = (f16x2){ (f16)v.x, (f16)v.y };
        }
    }
    const float ub = Ub[tid];

    // LDS: U tail [512 rows][64 f16] XOR-swizzled (G4: stride-128B rows would
    // be a 16-way conflict) + double-buffered h (f16[512]).
    __shared__ __align__(16) char utail[512 * 128];   // 64 KB
    __shared__ __align__(16) char hb[2][1024];        // 2 x 1 KB

    // Stage U tail: thread j converts its own row's k in [448,512).
    {
        const float4* tp = reinterpret_cast<const float4*>(Uw + (size_t)tid * 512 + KREG);
#pragma unroll
        for (int i = 0; i < 8; ++i) {
            float4 v0 = tp[2 * i], v1 = tp[2 * i + 1];
            f16x8 w = { (f16)v0.x, (f16)v0.y, (f16)v0.z, (f16)v0.w,
                        (f16)v1.x, (f16)v1.y, (f16)v1.z, (f16)v1.w };
            *reinterpret_cast<f16x8*>(utail + tid * 128 + ((16 * i) ^ ((tid & 7) << 4))) = w;
        }
    }

    float* const obase = out + (size_t)b * (T_STEPS * 512);

    // h_0 -> hb[0]
    *reinterpret_cast<f16*>(hb[0] + 2 * tid) = (f16)h0[b * 512 + tid];
    float wx = obase[tid];          // Wx row 0 (gemm_wx completed: same stream)
    __syncthreads();

    for (int t = 0; t < T_STEPS; ++t) {
        // Gather full h into the wave: lane l holds pairs 4l..4l+3 (16B).
        const uint4 vh = *reinterpret_cast<const uint4*>(hb[t & 1] + 16 * lane);
        // Prefetch next step's Wx (HBM latency hides under ~2200cy of VALU).
        float wxn = 0.0f;
        if (t < T_STEPS - 1) wxn = obase[(size_t)(t + 1) * 512 + tid];

        float a0 = 0.f, a1 = 0.f, a2 = 0.f, a3 = 0.f;
        // Register part: pairs 0..223. Pair q lives in lane q>>2, component q&3.
#pragma unroll
        for (int p = 0; p < NPREG; p += 4) {
            const int ln = p >> 2;
            const int s0 = __builtin_amdgcn_readlane((int)vh.x, ln);
            const int s1 = __builtin_amdgcn_readlane((int)vh.y, ln);
            const int s2 = __builtin_amdgcn_readlane((int)vh.z, ln);
            const int s3 = __builtin_amdgcn_readlane((int)vh.w, ln);
            a0 = FDOT2(bcast_pair(s0), u[p + 0], a0);
            a1 = FDOT2(bcast_pair(s1), u[p + 1], a1);
            a2 = FDOT2(bcast_pair(s2), u[p + 2], a2);
            a3 = FDOT2(bcast_pair(s3), u[p + 3], a3);
        }
        // Tail: pairs 224..255 (k in [448,512)), U from swizzled LDS.
#pragma unroll
        for (int i = 0; i < 8; ++i) {
            const uint4 ut = *reinterpret_cast<const uint4*>(
                utail + tid * 128 + ((16 * i) ^ ((tid & 7) << 4)));
            const int ln = 56 + i;
            const int s0 = __builtin_amdgcn_readlane((int)vh.x, ln);
            const int s1 = __builtin_amdgcn_readlane((int)vh.y, ln);
            const int s2 = __builtin_amdgcn_readlane((int)vh.z, ln);
            const int s3 = __builtin_amdgcn_readlane((int)vh.w, ln);
            a0 = FDOT2(bcast_pair(s0), __builtin_bit_cast(f16x2, ut.x), a0);
            a1 = FDOT2(bcast_pair(s1), __builtin_bit_cast(f16x2, ut.y), a1);
            a2 = FDOT2(bcast_pair(s2), __builtin_bit_cast(f16x2, ut.z), a2);
            a3 = FDOT2(bcast_pair(s3), __builtin_bit_cast(f16x2, ut.w), a3);
        }

        const float a  = wx + ((a0 + a1) + (a2 + a3)) + ub;
        const float ax = fabsf(a);
        const float e  = __expf(2.0f * ax);
        const float r1 = 1.0f - 2.0f / (e + 1.0f);     // tanh(|a|); e=inf -> 1
        const float h  = copysignf(r1, a);

        *reinterpret_cast<f16*>(hb[(t + 1) & 1] + 2 * tid) = (f16)h;
        obase[(size_t)t * 512 + tid] = h;              // overwrite consumed Wx
        wx = wxn;
        __syncthreads();   // h_t writes visible; old buffer fully consumed
    }
}

// ---------------------------------------------------------------------------
extern "C" void kernel_launch(void* const* d_in, const int* in_sizes, int n_in,
                              void* d_out, int out_size, void* d_ws, size_t ws_size,
                              hipStream_t stream) {
    const float* X  = (const float*)d_in[0];
    const float* h0 = (const float*)d_in[1];
    const float* Ww = (const float*)d_in[2];
    const float* Wb = (const float*)d_in[3];
    const float* Uw = (const float*)d_in[4];
    const float* Ub = (const float*)d_in[5];
    float* out = (float*)d_out;

    gemm_wx<<<dim3(512, 4), dim3(256), 0, stream>>>(X, Ww, Wb, out);
    rnn_scan<<<dim3(64), dim3(512), 0, stream>>>(out, h0, Uw, Ub);
}